// Round 17
// baseline (93.717 us; speedup 1.0000x reference)
//
#include <hip/hip_runtime.h>
#include <math.h>

#define D 256
#define H 512
#define TT 10
#define THRESH 0.4f
#define KS 8          // K steps of 32 (D = 256)
#define NSPLIT 16     // scan blocks per graph

typedef __attribute__((ext_vector_type(8))) _Float16 half8;
typedef __attribute__((ext_vector_type(4))) float f32x4;

// ---------------------------------------------------------------------------
// K0: swizzle W1 [D][H] f32 -> fp16 MFMA B-fragments in ws (256 KB).
// ---------------------------------------------------------------------------
__global__ __launch_bounds__(256) void w1_prep(const float* __restrict__ W1,
                                               short* __restrict__ W1s)
{
    const int tid = blockIdx.x * 256 + threadIdx.x;   // 16384 threads
    const int lane = tid & 63;
    const int cell = tid >> 6;                        // 0..255 = (n,k)
    const int k = cell & 7;
    const int n = cell >> 3;
    const int row0 = k * 32 + (lane >> 4) * 8;
    const int col = n * 16 + (lane & 15);
    _Float16 h8[8];
    #pragma unroll
    for (int i = 0; i < 8; ++i)
        h8[i] = (_Float16)W1[(size_t)(row0 + i) * H + col];   // RTN
    *reinterpret_cast<half8*>(W1s + (((size_t)n * 8 + k) * 64 + lane) * 8) =
        *reinterpret_cast<half8*>(h8);
}

// ---------------------------------------------------------------------------
// K1 (fused): waves 0-3 = R15 gate MLP (unchanged math); waves 4-7 =
// mask compaction (128 MB int32 -> 4 MB ballot bitmask), overlapped.
// 256 blocks (1/CU), 512 thr. Both halves execute exactly 3 __syncthreads.
// cmask layout: per 256-int group g (flat over B*S/256), 4 u64 words:
//   cmask[g*4+c] bit t = (mask[g*256 + 4t + c] != 0)   (ballot order)
// ---------------------------------------------------------------------------
__global__ __launch_bounds__(512, 1) void gate_fused(
    const float* __restrict__ h_sub,
    const short* __restrict__ W1s,
    const float* __restrict__ b1,
    const float* __restrict__ W2,
    const float* __restrict__ b2,
    const int*   __restrict__ mask,
    float* __restrict__ submask,
    unsigned* __restrict__ gbits,                 // [S/32]
    unsigned long long* __restrict__ cmask)       // [B*S/256][4]
{
    __shared__ __align__(16) short sB[65536];        // 128 KB phase buffer
    __shared__ float sb1[H], sw2[H];                 // 4 KB
    const int tid = threadIdx.x;       // 0..511
    const int lane = tid & 63;
    const int w = tid >> 6;            // wave 0..7
    const bool isGate = (w < 4);
    const int base = blockIdx.x * 256 + w * 64;      // gate waves only
    const float bb = b2[0];

    // ---- gate-side helpers (threads 0..255 only) ----
    auto stagePhase = [&](int p) {
        const char* gp = (const char*)W1s + (size_t)p * 131072 + (size_t)tid * 16;
        char* lp0 = (char*)sB + (size_t)tid * 16;
        #pragma unroll
        for (int i = 0; i < 32; ++i) {
            __builtin_amdgcn_global_load_lds(
                (const __attribute__((address_space(1))) void*)(gp + i * 4096),
                (__attribute__((address_space(3))) void*)(lp0 + i * 4096),
                16, 0, 0);
        }
    };

    // ---- mask-side helper (waves 4..7): unroll-4 groups for MLP ----
    const int mw = blockIdx.x * 4 + (w - 4);         // 0..1023
    const size_t g0 = (size_t)mw * 128;              // 128 groups per wave
    auto maskChunk = [&](int lo, int hi) {
        for (int g = lo; g < hi; g += 4) {
            int4 m4[4];
            #pragma unroll
            for (int u = 0; u < 4; ++u)
                m4[u] = *reinterpret_cast<const int4*>(
                    mask + (g0 + g + u) * 256 + (lane << 2));
            #pragma unroll
            for (int u = 0; u < 4; ++u) {
                unsigned long long c0 = __ballot(m4[u].x != 0);
                unsigned long long c1 = __ballot(m4[u].y != 0);
                unsigned long long c2 = __ballot(m4[u].z != 0);
                unsigned long long c3 = __ballot(m4[u].w != 0);
                if (lane == 0) {
                    unsigned long long* cp = cmask + (g0 + g + u) * 4;
                    cp[0] = c0; cp[1] = c1; cp[2] = c2; cp[3] = c3;
                }
            }
        }
    };

    half8 af[4][KS];
    float lp[4][4];

    // ================= segment 0 (before barrier 1) =================
    if (isGate) {
        stagePhase(0);
        sb1[tid] = b1[tid];       sb1[tid + 256] = b1[tid + 256];
        sw2[tid] = W2[tid];       sw2[tid + 256] = W2[tid + 256];
        #pragma unroll
        for (int s = 0; s < 4; ++s) {
            const int row = base + s * 16 + (lane & 15);
            const float* rp = h_sub + (size_t)row * D + (lane >> 4) * 8;
            #pragma unroll
            for (int k = 0; k < KS; ++k) {
                float x[8];
                *reinterpret_cast<float4*>(&x[0]) =
                    *reinterpret_cast<const float4*>(rp + k * 32);
                *reinterpret_cast<float4*>(&x[4]) =
                    *reinterpret_cast<const float4*>(rp + k * 32 + 4);
                _Float16 h8[8];
                #pragma unroll
                for (int i = 0; i < 8; ++i) h8[i] = (_Float16)x[i];
                af[s][k] = *reinterpret_cast<half8*>(h8);
            }
        }
        #pragma unroll
        for (int s = 0; s < 4; ++s)
            #pragma unroll
            for (int j = 0; j < 4; ++j) lp[s][j] = 0.f;
    } else {
        maskChunk(0, 32);
    }

    __syncthreads();   // B1: phase-0 sB + biases visible, vmem drained

    // ================= segment 1: gate phase 0 / mask =================
    if (isGate) {
        #pragma unroll
        for (int nn = 0; nn < 16; ++nn) {
            const int n = (nn + w * 4) & 15;
            f32x4 acc[4];
            #pragma unroll
            for (int s = 0; s < 4; ++s) acc[s] = (f32x4){0.f,0.f,0.f,0.f};
            __builtin_amdgcn_s_setprio(1);
            #pragma unroll
            for (int k = 0; k < KS; ++k) {
                half8 bh = *reinterpret_cast<const half8*>(
                    sB + ((n * 8 + k) * 64 + lane) * 8);
                acc[0] = __builtin_amdgcn_mfma_f32_16x16x32_f16(af[0][k], bh, acc[0], 0, 0, 0);
                acc[1] = __builtin_amdgcn_mfma_f32_16x16x32_f16(af[1][k], bh, acc[1], 0, 0, 0);
                acc[2] = __builtin_amdgcn_mfma_f32_16x16x32_f16(af[2][k], bh, acc[2], 0, 0, 0);
                acc[3] = __builtin_amdgcn_mfma_f32_16x16x32_f16(af[3][k], bh, acc[3], 0, 0, 0);
            }
            __builtin_amdgcn_s_setprio(0);
            const int hc = n * 16 + (lane & 15);
            const float b1h = sb1[hc], w2h = sw2[hc];
            #pragma unroll
            for (int s = 0; s < 4; ++s)
                #pragma unroll
                for (int j = 0; j < 4; ++j) {
                    float v = acc[s][j] + b1h;
                    v = v > 0.f ? v : 0.f;
                    lp[s][j] = fmaf(v, w2h, lp[s][j]);
                }
        }
    } else {
        maskChunk(32, 80);
    }

    __syncthreads();   // B2: all gate waves done reading phase-0 sB

    // ================= segment 2: restage / small mask chunk ==========
    if (isGate) stagePhase(1);
    else        maskChunk(80, 88);

    __syncthreads();   // B3: phase-1 sB visible, vmem drained

    // ================= segment 3: gate phase 1 + epilogue / mask ======
    if (isGate) {
        #pragma unroll
        for (int nn = 0; nn < 16; ++nn) {
            const int n = (nn + w * 4) & 15;
            f32x4 acc[4];
            #pragma unroll
            for (int s = 0; s < 4; ++s) acc[s] = (f32x4){0.f,0.f,0.f,0.f};
            __builtin_amdgcn_s_setprio(1);
            #pragma unroll
            for (int k = 0; k < KS; ++k) {
                half8 bh = *reinterpret_cast<const half8*>(
                    sB + ((n * 8 + k) * 64 + lane) * 8);
                acc[0] = __builtin_amdgcn_mfma_f32_16x16x32_f16(af[0][k], bh, acc[0], 0, 0, 0);
                acc[1] = __builtin_amdgcn_mfma_f32_16x16x32_f16(af[1][k], bh, acc[1], 0, 0, 0);
                acc[2] = __builtin_amdgcn_mfma_f32_16x16x32_f16(af[2][k], bh, acc[2], 0, 0, 0);
                acc[3] = __builtin_amdgcn_mfma_f32_16x16x32_f16(af[3][k], bh, acc[3], 0, 0, 0);
            }
            __builtin_amdgcn_s_setprio(0);
            const int hc = 256 + n * 16 + (lane & 15);
            const float b1h = sb1[hc], w2h = sw2[hc];
            #pragma unroll
            for (int s = 0; s < 4; ++s)
                #pragma unroll
                for (int j = 0; j < 4; ++j) {
                    float v = acc[s][j] + b1h;
                    v = v > 0.f ? v : 0.f;
                    lp[s][j] = fmaf(v, w2h, lp[s][j]);
                }
        }

        // epilogue: butterfly, sigmoid, gbits
        #pragma unroll
        for (int m = 1; m < 16; m <<= 1)
            #pragma unroll
            for (int s = 0; s < 4; ++s)
                #pragma unroll
                for (int j = 0; j < 4; ++j)
                    lp[s][j] += __shfl_xor(lp[s][j], m);

        const int g = lane >> 4;
        unsigned b0 = 0, b1w = 0;
        float sig[4][4];
        #pragma unroll
        for (int s = 0; s < 4; ++s)
            #pragma unroll
            for (int j = 0; j < 4; ++j) {
                sig[s][j] = 1.f / (1.f + expf(-(lp[s][j] + bb)));
                const int r = s * 16 + g * 4 + j;
                if (sig[s][j] > THRESH) {
                    if (r < 32) b0 |= 1u << r;
                    else        b1w |= 1u << (r - 32);
                }
            }
        b0  |= __shfl_xor(b0, 16);  b0  |= __shfl_xor(b0, 32);
        b1w |= __shfl_xor(b1w, 16); b1w |= __shfl_xor(b1w, 32);
        if (lane == 0) {
            gbits[blockIdx.x * 8 + w * 2 + 0] = b0;
            gbits[blockIdx.x * 8 + w * 2 + 1] = b1w;
        }
        if ((lane & 15) == 0)
            #pragma unroll
            for (int s = 0; s < 4; ++s)
                #pragma unroll
                for (int j = 0; j < 4; ++j)
                    submask[base + s * 16 + g * 4 + j] = sig[s][j];
    } else {
        maskChunk(88, 128);
    }
}

// ---------------------------------------------------------------------------
// K2a: gather using compact cmask (4 MB) + gbits; NSPLIT=16.
// bal[s] = cmask64[group][s] & ballot(gatebit) — identical decode to before.
// ---------------------------------------------------------------------------
__global__ __launch_bounds__(256) void seg_scan(
    const float* __restrict__ h_sub,            // [S][D]
    const unsigned long long* __restrict__ cmask, // [B*S/256][4]
    const unsigned* __restrict__ gbits,         // [S/32]
    float* __restrict__ psum,                   // [B*NSPLIT][D]
    int*   __restrict__ pcnt,                   // [B*NSPLIT]
    int S)
{
    const int i = blockIdx.x / NSPLIT;
    const int p = blockIdx.x % NSPLIT;
    const int tid = threadIdx.x;
    const int lane = tid & 63;
    const int w = tid >> 6;
    const int seg = S / NSPLIT;                 // 4096
    const int start = p * seg;
    const unsigned long long* cm =
        cmask + ((size_t)i * (S / 256) + (size_t)p * (seg / 256)) * 4;

    __shared__ unsigned sbits[4096 / 32];       // 128 words
    if (tid < seg / 32) sbits[tid] = gbits[(start >> 5) + tid];
    __syncthreads();

    float4 acc = make_float4(0.f, 0.f, 0.f, 0.f);
    int cnt = 0;

    #pragma unroll
    for (int it = 0; it < 4; ++it) {
        const int g = w * 4 + it;               // group within segment (16)
        const int j0 = g * 256 + (lane << 2);
        const unsigned bw = sbits[j0 >> 5];
        const int sh = j0 & 31;
        unsigned long long bal[4];
        bal[0] = __ballot((bw >> (sh + 0)) & 1u) & cm[(size_t)g * 4 + 0];
        bal[1] = __ballot((bw >> (sh + 1)) & 1u) & cm[(size_t)g * 4 + 1];
        bal[2] = __ballot((bw >> (sh + 2)) & 1u) & cm[(size_t)g * 4 + 2];
        bal[3] = __ballot((bw >> (sh + 3)) & 1u) & cm[(size_t)g * 4 + 3];
        #pragma unroll
        for (int s = 0; s < 4; ++s) {
            unsigned long long b = bal[s];
            while (b) {
                int t = __builtin_ctzll(b);
                b &= b - 1;
                int jj = start + g * 256 + (t << 2) + s;
                float4 hv = *reinterpret_cast<const float4*>(
                    h_sub + (size_t)jj * D + (lane << 2));
                acc.x += hv.x; acc.y += hv.y; acc.z += hv.z; acc.w += hv.w;
                cnt++;
            }
        }
    }

    __shared__ float ssum[4][D];
    __shared__ int   scnt[4];
    *reinterpret_cast<float4*>(&ssum[w][lane << 2]) = acc;
    if (lane == 0) scnt[w] = cnt;
    __syncthreads();

    float a = ssum[0][tid] + ssum[1][tid] + ssum[2][tid] + ssum[3][tid];
    psum[(size_t)blockIdx.x * D + tid] = a;
    if (tid == 0) pcnt[blockIdx.x] = scnt[0] + scnt[1] + scnt[2] + scnt[3];
}

// ---------------------------------------------------------------------------
// K2b: combine partials -> mean, cosine, classifier logits
// ---------------------------------------------------------------------------
__global__ __launch_bounds__(256) void seg_combine(
    const float* __restrict__ h_graph,  // [B][D]
    const float* __restrict__ psum,     // [B*NSPLIT][D]
    const int*   __restrict__ pcnt,     // [B*NSPLIT]
    const float* __restrict__ Wc,       // [2D][TT]
    const float* __restrict__ bc,       // [TT]
    float* __restrict__ logits,         // [B][TT]
    float* __restrict__ cos_ws)         // [B]
{
    const int i = blockIdx.x;
    const int tid = threadIdx.x;
    const int lane = tid & 63;
    const int w = tid >> 6;

    float a = 0.f;
    int c = 0;
    #pragma unroll
    for (int p = 0; p < NSPLIT; ++p) {
        a += psum[((size_t)i * NSPLIT + p) * D + tid];
        c += pcnt[i * NSPLIT + p];
    }
    a = (c > 0) ? (a / (float)c) : 0.f;
    const float g = h_graph[(size_t)i * D + tid];

    float r0 = a * a, r1 = g * g, r2 = a * g;
    #pragma unroll
    for (int m = 1; m < 64; m <<= 1) {
        r0 += __shfl_xor(r0, m);
        r1 += __shfl_xor(r1, m);
        r2 += __shfl_xor(r2, m);
    }
    __shared__ float red[4][3];
    if (lane == 0) { red[w][0] = r0; red[w][1] = r1; red[w][2] = r2; }
    __syncthreads();
    if (tid == 0) {
        float a2 = red[0][0] + red[1][0] + red[2][0] + red[3][0];
        float g2 = red[0][1] + red[1][1] + red[2][1] + red[3][1];
        float ag = red[0][2] + red[1][2] + red[2][2] + red[3][2];
        float an = sqrtf(a2), gn = sqrtf(g2);
        float cs = (c > 0) ? (ag / (fmaxf(an, 1e-12f) * fmaxf(gn, 1e-12f))) : 0.f;
        cos_ws[i] = cs;
    }

    float lg[TT];
    #pragma unroll
    for (int t = 0; t < TT; ++t)
        lg[t] = g * Wc[(size_t)tid * TT + t] + a * Wc[(size_t)(D + tid) * TT + t];
    #pragma unroll
    for (int m = 1; m < 64; m <<= 1)
        #pragma unroll
        for (int t = 0; t < TT; ++t) lg[t] += __shfl_xor(lg[t], m);
    __shared__ float lpart[4][TT];
    if (lane == 0)
        #pragma unroll
        for (int t = 0; t < TT; ++t) lpart[w][t] = lg[t];
    __syncthreads();
    if (tid < TT)
        logits[(size_t)i * TT + tid] =
            lpart[0][tid] + lpart[1][tid] + lpart[2][tid] + lpart[3][tid] + bc[tid];
}

// ---------------------------------------------------------------------------
__global__ void loss_kernel(const float* __restrict__ cos_ws,
                            float* __restrict__ out, int B)
{
    const int lane = threadIdx.x;
    float s = 0.f;
    for (int i = lane; i < B; i += 64) s += cos_ws[i];
    #pragma unroll
    for (int m = 1; m < 64; m <<= 1) s += __shfl_xor(s, m);
    if (lane == 0) out[0] = 1.0f - s / (float)B;
}

// ---------------------------------------------------------------------------
extern "C" void kernel_launch(void* const* d_in, const int* in_sizes, int n_in,
                              void* d_out, int out_size, void* d_ws, size_t ws_size,
                              hipStream_t stream)
{
    const float* h_graph = (const float*)d_in[0];
    const float* h_sub   = (const float*)d_in[1];
    const float* W1      = (const float*)d_in[2];
    const float* b1      = (const float*)d_in[3];
    const float* W2      = (const float*)d_in[4];
    const float* b2      = (const float*)d_in[5];
    const float* Wc      = (const float*)d_in[6];
    const float* bc      = (const float*)d_in[7];
    const int*   mask    = (const int*)d_in[8];

    const int B = in_sizes[0] / D;
    const int S = in_sizes[1] / D;

    float* out     = (float*)d_out;
    float* logits  = out;                       // [B*TT]
    float* loss    = out + (size_t)B * TT;      // [1]
    float* submask = loss + 1;                  // [S]

    char* ws = (char*)d_ws;
    short*    W1s    = (short*)ws;                       // 256 KB fp16 frags
    unsigned* gbits  = (unsigned*)(ws + 512 * 1024);     // 8 KB
    int*      pcnt   = (int*)(ws + 528 * 1024);          // 32 KB
    float*    cos_ws = (float*)(ws + 576 * 1024);        // 2 KB
    float*    psum   = (float*)(ws + 1024 * 1024);       // 8 MB
    unsigned long long* cmask =
        (unsigned long long*)(ws + 16 * 1024 * 1024);    // 4 MB

    w1_prep<<<64, 256, 0, stream>>>(W1, W1s);
    gate_fused<<<S / 256, 512, 0, stream>>>(
        h_sub, W1s, b1, W2, b2, mask, submask, gbits, cmask);
    seg_scan<<<B * NSPLIT, 256, 0, stream>>>(h_sub, cmask, gbits, psum, pcnt, S);
    seg_combine<<<B, 256, 0, stream>>>(h_graph, psum, pcnt, Wc, bc, logits, cos_ws);
    loss_kernel<<<1, 64, 0, stream>>>(cos_ws, loss, B);
}

// Round 18
// 78.133 us; speedup vs baseline: 1.1995x; 1.1995x over previous
//
#include <hip/hip_runtime.h>
#include <math.h>

#define D 256
#define H 512
#define TT 10
#define THRESH 0.4f
#define KS 8          // K steps of 32 (D = 256)
#define NSPLIT 16     // scan blocks per graph

typedef __attribute__((ext_vector_type(8))) _Float16 half8;
typedef __attribute__((ext_vector_type(4))) float f32x4;

// ---------------------------------------------------------------------------
// K0: swizzle W1 [D][H] f32 -> fp16 MFMA B-fragments in ws (256 KB).
// layout (half8 = 16B units): idx = (n*8 + k)*64 + lane
//   element i = W1[k*32 + (lane>>4)*8 + i][n*16 + (lane&15)]
// each n-tile (16 cols) is a contiguous 8 KB chunk.
// ---------------------------------------------------------------------------
__global__ __launch_bounds__(256) void w1_prep(const float* __restrict__ W1,
                                               short* __restrict__ W1s)
{
    const int tid = blockIdx.x * 256 + threadIdx.x;   // 16384 threads
    const int lane = tid & 63;
    const int cell = tid >> 6;                        // 0..255 = (n,k)
    const int k = cell & 7;
    const int n = cell >> 3;
    const int row0 = k * 32 + (lane >> 4) * 8;
    const int col = n * 16 + (lane & 15);
    _Float16 h8[8];
    #pragma unroll
    for (int i = 0; i < 8; ++i)
        h8[i] = (_Float16)W1[(size_t)(row0 + i) * H + col];   // RTN
    *reinterpret_cast<half8*>(W1s + (((size_t)n * 8 + k) * 64 + lane) * 8) =
        *reinterpret_cast<half8*>(h8);
}

// ---------------------------------------------------------------------------
// K1 (fused, UNCOUPLED): 512 blocks x 512 thr (2 blocks/CU).
// Waves 0-3: R11 gate pipeline (32 rows each, private 2x8KB LDS dbuf,
//   global_load_lds + counted vmcnt(8), chunk rotation, ZERO steady barriers).
// Waves 4-7: mask compaction 128MB int32 -> 4MB ballot bitmask, 8 loads
//   in flight, free-running.
// ONE __syncthreads total (prologue: sb1/sw2 + clean vmcnt for gate waves).
// Per SIMD: 2 gate + 2 mask waves = heterogeneous latency cover (m114).
// ---------------------------------------------------------------------------
__global__ __launch_bounds__(512, 4) void gate_fused(
    const float* __restrict__ h_sub,
    const short* __restrict__ W1s,
    const float* __restrict__ b1,
    const float* __restrict__ W2,
    const float* __restrict__ b2,
    const int*   __restrict__ mask,
    float* __restrict__ submask,
    unsigned* __restrict__ gbits,                 // [S/32]
    unsigned long long* __restrict__ cmask)       // [B*S/256][4]
{
    __shared__ __align__(16) short sW[4][2][4096];   // gate waves: 2x8KB each
    __shared__ float sb1[H], sw2[H];
    const int tid = threadIdx.x;       // 0..511
    const int lane = tid & 63;
    const int w = tid >> 6;            // wave 0..7
    const bool isGate = (w < 4);
    const float bb = b2[0];

    // gate-wave identifiers
    const int base = blockIdx.x * 128 + w * 32;      // rows (gate waves)
    const int rot = (blockIdx.x * 4 + w) & 31;       // chunk rotation

    half8 af[2][KS];

    if (isGate) {
        // stage b1 / W2 into LDS (256 gate threads cover 512 entries x2)
        int i = tid * 2;
        *reinterpret_cast<float2*>(&sb1[i]) = *reinterpret_cast<const float2*>(&b1[i]);
        *reinterpret_cast<float2*>(&sw2[i]) = *reinterpret_cast<const float2*>(&W2[i]);

        // A fragments fp16: 2 s-tiles x 8 k = 64 VGPR
        #pragma unroll
        for (int s = 0; s < 2; ++s) {
            const int row = base + s * 16 + (lane & 15);
            const float* rp = h_sub + (size_t)row * D + (lane >> 4) * 8;
            #pragma unroll
            for (int k = 0; k < KS; ++k) {
                float x[8];
                *reinterpret_cast<float4*>(&x[0]) =
                    *reinterpret_cast<const float4*>(rp + k * 32);
                *reinterpret_cast<float4*>(&x[4]) =
                    *reinterpret_cast<const float4*>(rp + k * 32 + 4);
                _Float16 h8[8];
                #pragma unroll
                for (int i2 = 0; i2 < 8; ++i2) h8[i2] = (_Float16)x[i2];
                af[s][k] = *reinterpret_cast<half8*>(h8);
            }
        }
    }

    // ONE barrier: sb1/sw2 visible; every wave's own vmem drained
    // (hipcc emits s_waitcnt vmcnt(0) before s_barrier) -> gate waves'
    // counted-vmcnt bookkeeping starts from zero.
    __syncthreads();

    if (isGate) {
        // ---- R11 gate pipeline (verbatim structure, known-good) ----
        auto stage = [&](int c, int b) {
            const char* gp = (const char*)W1s + ((size_t)(c & 31) << 13)
                           + (size_t)lane * 16;
            char* lp0 = (char*)&sW[w][b][0] + lane * 16;
            #pragma unroll
            for (int i = 0; i < 8; ++i) {
                __builtin_amdgcn_global_load_lds(
                    (const __attribute__((address_space(1))) void*)(gp + i * 1024),
                    (__attribute__((address_space(3))) void*)(lp0 + i * 1024),
                    16, 0, 0);
            }
        };

        stage(rot, 0);
        stage(rot + 1, 1);

        float lp[2][4] = {{0.f,0.f,0.f,0.f},{0.f,0.f,0.f,0.f}};

        for (int cc = 0; cc < 32; ++cc) {
            if (cc < 31) asm volatile("s_waitcnt vmcnt(8)" ::: "memory");
            else         asm volatile("s_waitcnt vmcnt(0)" ::: "memory");
            __builtin_amdgcn_sched_barrier(0);

            const int c = (cc + rot) & 31;       // actual n-tile index
            const short* buf = &sW[w][cc & 1][0];
            f32x4 acc[2];
            acc[0] = (f32x4){0.f,0.f,0.f,0.f};
            acc[1] = (f32x4){0.f,0.f,0.f,0.f};

            #pragma unroll
            for (int k = 0; k < KS; ++k) {
                half8 bh = *reinterpret_cast<const half8*>(buf + (k * 64 + lane) * 8);
                acc[0] = __builtin_amdgcn_mfma_f32_16x16x32_f16(af[0][k], bh, acc[0], 0, 0, 0);
                acc[1] = __builtin_amdgcn_mfma_f32_16x16x32_f16(af[1][k], bh, acc[1], 0, 0, 0);
            }

            const int h = c * 16 + (lane & 15);
            const float b1h = sb1[h], w2h = sw2[h];
            #pragma unroll
            for (int s = 0; s < 2; ++s)
                #pragma unroll
                for (int j = 0; j < 4; ++j) {
                    float v = acc[s][j] + b1h;
                    v = v > 0.f ? v : 0.f;
                    lp[s][j] = fmaf(v, w2h, lp[s][j]);
                }

            __builtin_amdgcn_sched_barrier(0);
            if (cc < 30) stage(cc + rot + 2, cc & 1);
        }

        // butterfly over the 16 h-cols
        #pragma unroll
        for (int m = 1; m < 16; m <<= 1)
            #pragma unroll
            for (int s = 0; s < 2; ++s)
                #pragma unroll
                for (int j = 0; j < 4; ++j)
                    lp[s][j] += __shfl_xor(lp[s][j], m);

        const int g = lane >> 4;
        unsigned bits = 0;
        float sig[2][4];
        #pragma unroll
        for (int s = 0; s < 2; ++s)
            #pragma unroll
            for (int j = 0; j < 4; ++j) {
                sig[s][j] = 1.f / (1.f + expf(-(lp[s][j] + bb)));
                if (sig[s][j] > THRESH) bits |= 1u << (s * 16 + g * 4 + j);
            }
        bits |= __shfl_xor(bits, 16);
        bits |= __shfl_xor(bits, 32);
        if (lane == 0) gbits[blockIdx.x * 4 + w] = bits;

        if ((lane & 15) == 0)
            #pragma unroll
            for (int s = 0; s < 2; ++s)
                #pragma unroll
                for (int j = 0; j < 4; ++j)
                    submask[base + s * 16 + g * 4 + j] = sig[s][j];
    } else {
        // ---- mask compaction: 64 groups/wave, 8 loads in flight ----
        const int mw = blockIdx.x * 4 + (w - 4);     // 0..2047
        const size_t g0 = (size_t)mw * 64;
        for (int it = 0; it < 8; ++it) {
            int4 m4[8];
            #pragma unroll
            for (int u = 0; u < 8; ++u)
                m4[u] = *reinterpret_cast<const int4*>(
                    mask + (g0 + it * 8 + u) * 256 + (lane << 2));
            #pragma unroll
            for (int u = 0; u < 8; ++u) {
                unsigned long long c0 = __ballot(m4[u].x != 0);
                unsigned long long c1 = __ballot(m4[u].y != 0);
                unsigned long long c2 = __ballot(m4[u].z != 0);
                unsigned long long c3 = __ballot(m4[u].w != 0);
                if (lane == 0) {
                    unsigned long long* cp = cmask + (g0 + it * 8 + u) * 4;
                    cp[0] = c0; cp[1] = c1; cp[2] = c2; cp[3] = c3;
                }
            }
        }
    }
}

// ---------------------------------------------------------------------------
// K2a: gather using compact cmask (4 MB) + gbits; NSPLIT=16. (R17, passed)
// ---------------------------------------------------------------------------
__global__ __launch_bounds__(256) void seg_scan(
    const float* __restrict__ h_sub,              // [S][D]
    const unsigned long long* __restrict__ cmask, // [B*S/256][4]
    const unsigned* __restrict__ gbits,           // [S/32]
    float* __restrict__ psum,                     // [B*NSPLIT][D]
    int*   __restrict__ pcnt,                     // [B*NSPLIT]
    int S)
{
    const int i = blockIdx.x / NSPLIT;
    const int p = blockIdx.x % NSPLIT;
    const int tid = threadIdx.x;
    const int lane = tid & 63;
    const int w = tid >> 6;
    const int seg = S / NSPLIT;                 // 4096
    const int start = p * seg;
    const unsigned long long* cm =
        cmask + ((size_t)i * (S / 256) + (size_t)p * (seg / 256)) * 4;

    __shared__ unsigned sbits[4096 / 32];       // 128 words
    if (tid < seg / 32) sbits[tid] = gbits[(start >> 5) + tid];
    __syncthreads();

    float4 acc = make_float4(0.f, 0.f, 0.f, 0.f);
    int cnt = 0;

    #pragma unroll
    for (int it = 0; it < 4; ++it) {
        const int g = w * 4 + it;               // group within segment
        const int j0 = g * 256 + (lane << 2);
        const unsigned bw = sbits[j0 >> 5];
        const int sh = j0 & 31;
        unsigned long long bal[4];
        bal[0] = __ballot((bw >> (sh + 0)) & 1u) & cm[(size_t)g * 4 + 0];
        bal[1] = __ballot((bw >> (sh + 1)) & 1u) & cm[(size_t)g * 4 + 1];
        bal[2] = __ballot((bw >> (sh + 2)) & 1u) & cm[(size_t)g * 4 + 2];
        bal[3] = __ballot((bw >> (sh + 3)) & 1u) & cm[(size_t)g * 4 + 3];
        #pragma unroll
        for (int s = 0; s < 4; ++s) {
            unsigned long long b = bal[s];
            while (b) {
                int t = __builtin_ctzll(b);
                b &= b - 1;
                int jj = start + g * 256 + (t << 2) + s;
                float4 hv = *reinterpret_cast<const float4*>(
                    h_sub + (size_t)jj * D + (lane << 2));
                acc.x += hv.x; acc.y += hv.y; acc.z += hv.z; acc.w += hv.w;
                cnt++;
            }
        }
    }

    __shared__ float ssum[4][D];
    __shared__ int   scnt[4];
    *reinterpret_cast<float4*>(&ssum[w][lane << 2]) = acc;
    if (lane == 0) scnt[w] = cnt;
    __syncthreads();

    float a = ssum[0][tid] + ssum[1][tid] + ssum[2][tid] + ssum[3][tid];
    psum[(size_t)blockIdx.x * D + tid] = a;
    if (tid == 0) pcnt[blockIdx.x] = scnt[0] + scnt[1] + scnt[2] + scnt[3];
}

// ---------------------------------------------------------------------------
// K2b: combine partials -> mean, cosine, classifier logits
// ---------------------------------------------------------------------------
__global__ __launch_bounds__(256) void seg_combine(
    const float* __restrict__ h_graph,  // [B][D]
    const float* __restrict__ psum,     // [B*NSPLIT][D]
    const int*   __restrict__ pcnt,     // [B*NSPLIT]
    const float* __restrict__ Wc,       // [2D][TT]
    const float* __restrict__ bc,       // [TT]
    float* __restrict__ logits,         // [B][TT]
    float* __restrict__ cos_ws)         // [B]
{
    const int i = blockIdx.x;
    const int tid = threadIdx.x;
    const int lane = tid & 63;
    const int w = tid >> 6;

    float a = 0.f;
    int c = 0;
    #pragma unroll
    for (int p = 0; p < NSPLIT; ++p) {
        a += psum[((size_t)i * NSPLIT + p) * D + tid];
        c += pcnt[i * NSPLIT + p];
    }
    a = (c > 0) ? (a / (float)c) : 0.f;
    const float g = h_graph[(size_t)i * D + tid];

    float r0 = a * a, r1 = g * g, r2 = a * g;
    #pragma unroll
    for (int m = 1; m < 64; m <<= 1) {
        r0 += __shfl_xor(r0, m);
        r1 += __shfl_xor(r1, m);
        r2 += __shfl_xor(r2, m);
    }
    __shared__ float red[4][3];
    if (lane == 0) { red[w][0] = r0; red[w][1] = r1; red[w][2] = r2; }
    __syncthreads();
    if (tid == 0) {
        float a2 = red[0][0] + red[1][0] + red[2][0] + red[3][0];
        float g2 = red[0][1] + red[1][1] + red[2][1] + red[3][1];
        float ag = red[0][2] + red[1][2] + red[2][2] + red[3][2];
        float an = sqrtf(a2), gn = sqrtf(g2);
        float cs = (c > 0) ? (ag / (fmaxf(an, 1e-12f) * fmaxf(gn, 1e-12f))) : 0.f;
        cos_ws[i] = cs;
    }

    float lg[TT];
    #pragma unroll
    for (int t = 0; t < TT; ++t)
        lg[t] = g * Wc[(size_t)tid * TT + t] + a * Wc[(size_t)(D + tid) * TT + t];
    #pragma unroll
    for (int m = 1; m < 64; m <<= 1)
        #pragma unroll
        for (int t = 0; t < TT; ++t) lg[t] += __shfl_xor(lg[t], m);
    __shared__ float lpart[4][TT];
    if (lane == 0)
        #pragma unroll
        for (int t = 0; t < TT; ++t) lpart[w][t] = lg[t];
    __syncthreads();
    if (tid < TT)
        logits[(size_t)i * TT + tid] =
            lpart[0][tid] + lpart[1][tid] + lpart[2][tid] + lpart[3][tid] + bc[tid];
}

// ---------------------------------------------------------------------------
__global__ void loss_kernel(const float* __restrict__ cos_ws,
                            float* __restrict__ out, int B)
{
    const int lane = threadIdx.x;
    float s = 0.f;
    for (int i = lane; i < B; i += 64) s += cos_ws[i];
    #pragma unroll
    for (int m = 1; m < 64; m <<= 1) s += __shfl_xor(s, m);
    if (lane == 0) out[0] = 1.0f - s / (float)B;
}

// ---------------------------------------------------------------------------
extern "C" void kernel_launch(void* const* d_in, const int* in_sizes, int n_in,
                              void* d_out, int out_size, void* d_ws, size_t ws_size,
                              hipStream_t stream)
{
    const float* h_graph = (const float*)d_in[0];
    const float* h_sub   = (const float*)d_in[1];
    const float* W1      = (const float*)d_in[2];
    const float* b1      = (const float*)d_in[3];
    const float* W2      = (const float*)d_in[4];
    const float* b2      = (const float*)d_in[5];
    const float* Wc      = (const float*)d_in[6];
    const float* bc      = (const float*)d_in[7];
    const int*   mask    = (const int*)d_in[8];

    const int B = in_sizes[0] / D;
    const int S = in_sizes[1] / D;

    float* out     = (float*)d_out;
    float* logits  = out;                       // [B*TT]
    float* loss    = out + (size_t)B * TT;      // [1]
    float* submask = loss + 1;                  // [S]

    char* ws = (char*)d_ws;
    short*    W1s    = (short*)ws;                       // 256 KB fp16 frags
    unsigned* gbits  = (unsigned*)(ws + 512 * 1024);     // 8 KB
    int*      pcnt   = (int*)(ws + 528 * 1024);          // 32 KB
    float*    cos_ws = (float*)(ws + 576 * 1024);        // 2 KB
    float*    psum   = (float*)(ws + 1024 * 1024);       // 8 MB
    unsigned long long* cmask =
        (unsigned long long*)(ws + 16 * 1024 * 1024);    // 4 MB

    w1_prep<<<64, 256, 0, stream>>>(W1, W1s);
    gate_fused<<<S / 128, 512, 0, stream>>>(
        h_sub, W1s, b1, W2, b2, mask, submask, gbits, cmask);
    seg_scan<<<B * NSPLIT, 256, 0, stream>>>(h_sub, cmask, gbits, psum, pcnt, S);
    seg_combine<<<B, 256, 0, stream>>>(h_graph, psum, pcnt, Wc, bc, logits, cos_ws);
    loss_kernel<<<1, 64, 0, stream>>>(cos_ws, loss, B);
}

// Round 19
// 71.656 us; speedup vs baseline: 1.3079x; 1.0904x over previous
//
#include <hip/hip_runtime.h>
#include <math.h>

#define D 256
#define H 512
#define TT 10
#define THRESH 0.4f
#define KS 8          // K steps of 32 (D = 256)
#define NSPLIT 16     // scan blocks per graph

typedef __attribute__((ext_vector_type(8))) _Float16 half8;
typedef __attribute__((ext_vector_type(4))) float f32x4;

// ---------------------------------------------------------------------------
// K0: swizzle W1 [D][H] f32 -> fp16 MFMA B-fragments in ws (256 KB).
// layout (half8 = 16B units): idx = (n*8 + k)*64 + lane
//   element i = W1[k*32 + (lane>>4)*8 + i][n*16 + (lane&15)]
// n-tile n = 8 KB; 64-col chunk c (4 n-tiles) = contiguous 32 KB.
// ---------------------------------------------------------------------------
__global__ __launch_bounds__(256) void w1_prep(const float* __restrict__ W1,
                                               short* __restrict__ W1s)
{
    const int tid = blockIdx.x * 256 + threadIdx.x;   // 16384 threads
    const int lane = tid & 63;
    const int cell = tid >> 6;                        // 0..255 = (n,k)
    const int k = cell & 7;
    const int n = cell >> 3;
    const int row0 = k * 32 + (lane >> 4) * 8;
    const int col = n * 16 + (lane & 15);
    _Float16 h8[8];
    #pragma unroll
    for (int i = 0; i < 8; ++i)
        h8[i] = (_Float16)W1[(size_t)(row0 + i) * H + col];   // RTN
    *reinterpret_cast<half8*>(W1s + (((size_t)n * 8 + k) * 64 + lane) * 8) =
        *reinterpret_cast<half8*>(h8);
}

// ---------------------------------------------------------------------------
// K1: gate MLP, m97-class structure. 512 blocks x 256 thr (2 blocks/CU),
// wave = 32 rows (A fp16 in 64 VGPR). B streamed in 64-col chunks (32 KB)
// SHARED by all 4 waves: 2 x 32 KB LDS dbuf, global_load_lds(16B),
// counted vmcnt(8), raw s_barrier pairs. 4 n-tiles/chunk -> 8 independent
// acc chains, 64 MFMAs per barrier-pair. B L2 traffic 128 MB total.
// LDS 68 KB -> 2 blocks/CU = 2 waves/SIMD; VGPR ~120 (<=128).
// ---------------------------------------------------------------------------
__global__ __launch_bounds__(256, 2) void gate_mfma(
    const float* __restrict__ h_sub,
    const short* __restrict__ W1s,
    const float* __restrict__ b1,
    const float* __restrict__ W2,
    const float* __restrict__ b2,
    float* __restrict__ submask,
    unsigned* __restrict__ gbits)      // [S/32]
{
    __shared__ __align__(16) short sB[2][16384];   // 2 x 32 KB chunk buffers
    __shared__ float sb1[H], sw2[H];
    const int tid = threadIdx.x;       // 0..255
    const int lane = tid & 63;
    const int w = tid >> 6;            // wave 0..3
    const int base = blockIdx.x * 128 + w * 32;
    const int rot = blockIdx.x & 7;    // per-block chunk rotation (L2 spread)
    const float bb = b2[0];

    // biases into LDS
    {
        int i = tid * 2;
        *reinterpret_cast<float2*>(&sb1[i]) = *reinterpret_cast<const float2*>(&b1[i]);
        *reinterpret_cast<float2*>(&sw2[i]) = *reinterpret_cast<const float2*>(&W2[i]);
    }

    // A fragments fp16: 2 s-tiles x 8 k = 64 VGPR
    half8 af[2][KS];
    #pragma unroll
    for (int s = 0; s < 2; ++s) {
        const int row = base + s * 16 + (lane & 15);
        const float* rp = h_sub + (size_t)row * D + (lane >> 4) * 8;
        #pragma unroll
        for (int k = 0; k < KS; ++k) {
            float x[8];
            *reinterpret_cast<float4*>(&x[0]) =
                *reinterpret_cast<const float4*>(rp + k * 32);
            *reinterpret_cast<float4*>(&x[4]) =
                *reinterpret_cast<const float4*>(rp + k * 32 + 4);
            _Float16 h8[8];
            #pragma unroll
            for (int i = 0; i < 8; ++i) h8[i] = (_Float16)x[i];
            af[s][k] = *reinterpret_cast<half8*>(h8);
        }
    }

    // one full barrier: biases visible, ALL prologue vmem drained
    // (hipcc emits s_waitcnt vmcnt(0) before s_barrier for __syncthreads)
    // -> counted-vmcnt bookkeeping starts from zero.
    __syncthreads();

    // stage 64-col chunk (cc+rot)&7 (32 KB) into buffer b: 8 loads/thread
    auto stage = [&](int cc, int b) {
        const int c = (cc + rot) & 7;
        const char* gp = (const char*)W1s + ((size_t)c << 15) + (size_t)tid * 16;
        char* lp0 = (char*)&sB[b][0] + (size_t)tid * 16;
        #pragma unroll
        for (int i = 0; i < 8; ++i) {
            __builtin_amdgcn_global_load_lds(
                (const __attribute__((address_space(1))) void*)(gp + i * 4096),
                (__attribute__((address_space(3))) void*)(lp0 + i * 4096),
                16, 0, 0);
        }
    };

    stage(0, 0);
    stage(1, 1);

    float lp[2][4] = {{0.f,0.f,0.f,0.f},{0.f,0.f,0.f,0.f}};

    for (int cc = 0; cc < 8; ++cc) {
        // chunk cc landed; chunk cc+1's 8 loads stay in flight
        if (cc < 7) asm volatile("s_waitcnt vmcnt(8)" ::: "memory");
        else        asm volatile("s_waitcnt vmcnt(0)" ::: "memory");
        __builtin_amdgcn_s_barrier();
        __builtin_amdgcn_sched_barrier(0);

        const short* buf = &sB[cc & 1][0];
        const int c = (cc + rot) & 7;

        // 8 independent chains: acc[s][nt], s=0..1, nt=0..3
        f32x4 acc[2][4];
        #pragma unroll
        for (int s = 0; s < 2; ++s)
            #pragma unroll
            for (int nt = 0; nt < 4; ++nt)
                acc[s][nt] = (f32x4){0.f,0.f,0.f,0.f};

        __builtin_amdgcn_s_setprio(1);
        #pragma unroll
        for (int k = 0; k < KS; ++k) {
            half8 bh0 = *reinterpret_cast<const half8*>(buf + ((0 * 8 + k) * 64 + lane) * 8);
            half8 bh1 = *reinterpret_cast<const half8*>(buf + ((1 * 8 + k) * 64 + lane) * 8);
            half8 bh2 = *reinterpret_cast<const half8*>(buf + ((2 * 8 + k) * 64 + lane) * 8);
            half8 bh3 = *reinterpret_cast<const half8*>(buf + ((3 * 8 + k) * 64 + lane) * 8);
            acc[0][0] = __builtin_amdgcn_mfma_f32_16x16x32_f16(af[0][k], bh0, acc[0][0], 0, 0, 0);
            acc[1][0] = __builtin_amdgcn_mfma_f32_16x16x32_f16(af[1][k], bh0, acc[1][0], 0, 0, 0);
            acc[0][1] = __builtin_amdgcn_mfma_f32_16x16x32_f16(af[0][k], bh1, acc[0][1], 0, 0, 0);
            acc[1][1] = __builtin_amdgcn_mfma_f32_16x16x32_f16(af[1][k], bh1, acc[1][1], 0, 0, 0);
            acc[0][2] = __builtin_amdgcn_mfma_f32_16x16x32_f16(af[0][k], bh2, acc[0][2], 0, 0, 0);
            acc[1][2] = __builtin_amdgcn_mfma_f32_16x16x32_f16(af[1][k], bh2, acc[1][2], 0, 0, 0);
            acc[0][3] = __builtin_amdgcn_mfma_f32_16x16x32_f16(af[0][k], bh3, acc[0][3], 0, 0, 0);
            acc[1][3] = __builtin_amdgcn_mfma_f32_16x16x32_f16(af[1][k], bh3, acc[1][3], 0, 0, 0);
        }
        __builtin_amdgcn_s_setprio(0);

        // epilogue: 4 n-tiles x 16 h-cols: +b1, relu, dot W2
        #pragma unroll
        for (int nt = 0; nt < 4; ++nt) {
            const int hc = c * 64 + nt * 16 + (lane & 15);
            const float b1h = sb1[hc], w2h = sw2[hc];
            #pragma unroll
            for (int s = 0; s < 2; ++s)
                #pragma unroll
                for (int j = 0; j < 4; ++j) {
                    float v = acc[s][nt][j] + b1h;
                    v = v > 0.f ? v : 0.f;
                    lp[s][j] = fmaf(v, w2h, lp[s][j]);
                }
        }

        __builtin_amdgcn_sched_barrier(0);
        __builtin_amdgcn_s_barrier();        // all waves done reading buf
        if (cc < 6) stage(cc + 2, cc & 1);   // refill finished buffer
    }

    // butterfly over the 16 h-cols (low 4 lane bits)
    #pragma unroll
    for (int m = 1; m < 16; m <<= 1)
        #pragma unroll
        for (int s = 0; s < 2; ++s)
            #pragma unroll
            for (int j = 0; j < 4; ++j)
                lp[s][j] += __shfl_xor(lp[s][j], m);

    // rows: s*16 + g*4 + j  (g = lane>>4)
    const int g = lane >> 4;
    unsigned bits = 0;
    float sig[2][4];
    #pragma unroll
    for (int s = 0; s < 2; ++s)
        #pragma unroll
        for (int j = 0; j < 4; ++j) {
            sig[s][j] = 1.f / (1.f + expf(-(lp[s][j] + bb)));
            if (sig[s][j] > THRESH) bits |= 1u << (s * 16 + g * 4 + j);
        }
    bits |= __shfl_xor(bits, 16);
    bits |= __shfl_xor(bits, 32);
    if (lane == 0) gbits[blockIdx.x * 4 + w] = bits;

    if ((lane & 15) == 0)
        #pragma unroll
        for (int s = 0; s < 2; ++s)
            #pragma unroll
            for (int j = 0; j < 4; ++j)
                submask[base + s * 16 + g * 4 + j] = sig[s][j];
}

// ---------------------------------------------------------------------------
// K2a: mask scan (R16 verbatim): 4 int4 prefetched, NSPLIT=16.
// ---------------------------------------------------------------------------
__global__ __launch_bounds__(256) void seg_scan(
    const float* __restrict__ h_sub,    // [S][D]
    const int*   __restrict__ mask,     // [B][S]
    const unsigned* __restrict__ gbits, // [S/32]
    float* __restrict__ psum,           // [B*NSPLIT][D]
    int*   __restrict__ pcnt,           // [B*NSPLIT]
    int S)
{
    const int i = blockIdx.x / NSPLIT;
    const int p = blockIdx.x % NSPLIT;
    const int tid = threadIdx.x;
    const int lane = tid & 63;
    const int w = tid >> 6;
    const int seg = S / NSPLIT;                 // 4096
    const int start = p * seg;
    const int* mrow = mask + (size_t)i * S + start;

    __shared__ unsigned sbits[4096 / 32];       // 128 words
    if (tid < seg / 32) sbits[tid] = gbits[(start >> 5) + tid];

    const int wbase = w * 1024;
    int4 m4[4];
    #pragma unroll
    for (int it = 0; it < 4; ++it)
        m4[it] = *reinterpret_cast<const int4*>(mrow + wbase + it * 256 + (lane << 2));

    __syncthreads();

    float4 acc = make_float4(0.f, 0.f, 0.f, 0.f);
    int cnt = 0;

    #pragma unroll
    for (int it = 0; it < 4; ++it) {
        const int j0 = wbase + it * 256 + (lane << 2);
        const unsigned bw = sbits[j0 >> 5];
        const int sh = j0 & 31;
        unsigned long long bal[4];
        bal[0] = __ballot((m4[it].x != 0) & ((bw >> (sh + 0)) & 1u));
        bal[1] = __ballot((m4[it].y != 0) & ((bw >> (sh + 1)) & 1u));
        bal[2] = __ballot((m4[it].z != 0) & ((bw >> (sh + 2)) & 1u));
        bal[3] = __ballot((m4[it].w != 0) & ((bw >> (sh + 3)) & 1u));
        #pragma unroll
        for (int s = 0; s < 4; ++s) {
            unsigned long long b = bal[s];
            while (b) {
                int t = __builtin_ctzll(b);
                b &= b - 1;
                int jj = start + wbase + it * 256 + (t << 2) + s;
                float4 hv = *reinterpret_cast<const float4*>(
                    h_sub + (size_t)jj * D + (lane << 2));
                acc.x += hv.x; acc.y += hv.y; acc.z += hv.z; acc.w += hv.w;
                cnt++;
            }
        }
    }

    __shared__ float ssum[4][D];
    __shared__ int   scnt[4];
    *reinterpret_cast<float4*>(&ssum[w][lane << 2]) = acc;
    if (lane == 0) scnt[w] = cnt;
    __syncthreads();

    float a = ssum[0][tid] + ssum[1][tid] + ssum[2][tid] + ssum[3][tid];
    psum[(size_t)blockIdx.x * D + tid] = a;
    if (tid == 0) pcnt[blockIdx.x] = scnt[0] + scnt[1] + scnt[2] + scnt[3];
}

// ---------------------------------------------------------------------------
// K2b: combine partials -> mean, cosine, classifier logits
// ---------------------------------------------------------------------------
__global__ __launch_bounds__(256) void seg_combine(
    const float* __restrict__ h_graph,  // [B][D]
    const float* __restrict__ psum,     // [B*NSPLIT][D]
    const int*   __restrict__ pcnt,     // [B*NSPLIT]
    const float* __restrict__ Wc,       // [2D][TT]
    const float* __restrict__ bc,       // [TT]
    float* __restrict__ logits,         // [B][TT]
    float* __restrict__ cos_ws)         // [B]
{
    const int i = blockIdx.x;
    const int tid = threadIdx.x;
    const int lane = tid & 63;
    const int w = tid >> 6;

    float a = 0.f;
    int c = 0;
    #pragma unroll
    for (int p = 0; p < NSPLIT; ++p) {
        a += psum[((size_t)i * NSPLIT + p) * D + tid];
        c += pcnt[i * NSPLIT + p];
    }
    a = (c > 0) ? (a / (float)c) : 0.f;
    const float g = h_graph[(size_t)i * D + tid];

    float r0 = a * a, r1 = g * g, r2 = a * g;
    #pragma unroll
    for (int m = 1; m < 64; m <<= 1) {
        r0 += __shfl_xor(r0, m);
        r1 += __shfl_xor(r1, m);
        r2 += __shfl_xor(r2, m);
    }
    __shared__ float red[4][3];
    if (lane == 0) { red[w][0] = r0; red[w][1] = r1; red[w][2] = r2; }
    __syncthreads();
    if (tid == 0) {
        float a2 = red[0][0] + red[1][0] + red[2][0] + red[3][0];
        float g2 = red[0][1] + red[1][1] + red[2][1] + red[3][1];
        float ag = red[0][2] + red[1][2] + red[2][2] + red[3][2];
        float an = sqrtf(a2), gn = sqrtf(g2);
        float cs = (c > 0) ? (ag / (fmaxf(an, 1e-12f) * fmaxf(gn, 1e-12f))) : 0.f;
        cos_ws[i] = cs;
    }

    float lg[TT];
    #pragma unroll
    for (int t = 0; t < TT; ++t)
        lg[t] = g * Wc[(size_t)tid * TT + t] + a * Wc[(size_t)(D + tid) * TT + t];
    #pragma unroll
    for (int m = 1; m < 64; m <<= 1)
        #pragma unroll
        for (int t = 0; t < TT; ++t) lg[t] += __shfl_xor(lg[t], m);
    __shared__ float lpart[4][TT];
    if (lane == 0)
        #pragma unroll
        for (int t = 0; t < TT; ++t) lpart[w][t] = lg[t];
    __syncthreads();
    if (tid < TT)
        logits[(size_t)i * TT + tid] =
            lpart[0][tid] + lpart[1][tid] + lpart[2][tid] + lpart[3][tid] + bc[tid];
}

// ---------------------------------------------------------------------------
__global__ void loss_kernel(const float* __restrict__ cos_ws,
                            float* __restrict__ out, int B)
{
    const int lane = threadIdx.x;
    float s = 0.f;
    for (int i = lane; i < B; i += 64) s += cos_ws[i];
    #pragma unroll
    for (int m = 1; m < 64; m <<= 1) s += __shfl_xor(s, m);
    if (lane == 0) out[0] = 1.0f - s / (float)B;
}

// ---------------------------------------------------------------------------
extern "C" void kernel_launch(void* const* d_in, const int* in_sizes, int n_in,
                              void* d_out, int out_size, void* d_ws, size_t ws_size,
                              hipStream_t stream)
{
    const float* h_graph = (const float*)d_in[0];
    const float* h_sub   = (const float*)d_in[1];
    const float* W1      = (const float*)d_in[2];
    const float* b1      = (const float*)d_in[3];
    const float* W2      = (const float*)d_in[4];
    const float* b2      = (const float*)d_in[5];
    const float* Wc      = (const float*)d_in[6];
    const float* bc      = (const float*)d_in[7];
    const int*   mask    = (const int*)d_in[8];

    const int B = in_sizes[0] / D;
    const int S = in_sizes[1] / D;

    float* out     = (float*)d_out;
    float* logits  = out;                       // [B*TT]
    float* loss    = out + (size_t)B * TT;      // [1]
    float* submask = loss + 1;                  // [S]

    char* ws = (char*)d_ws;
    short*    W1s    = (short*)ws;                       // 256 KB fp16 frags
    unsigned* gbits  = (unsigned*)(ws + 512 * 1024);     // 8 KB
    int*      pcnt   = (int*)(ws + 528 * 1024);          // 32 KB
    float*    cos_ws = (float*)(ws + 576 * 1024);        // 2 KB
    float*    psum   = (float*)(ws + 1024 * 1024);       // 8 MB

    w1_prep<<<64, 256, 0, stream>>>(W1, W1s);
    gate_mfma<<<S / 128, 256, 0, stream>>>(h_sub, W1s, b1, W2, b2, submask, gbits);
    seg_scan<<<B * NSPLIT, 256, 0, stream>>>(h_sub, mask, gbits, psum, pcnt, S);
    seg_combine<<<B, 256, 0, stream>>>(h_graph, psum, pcnt, Wc, bc, logits, cos_ws);
    loss_kernel<<<1, 64, 0, stream>>>(cos_ws, loss, B);
}